// Round 1
// baseline (49.830 us; speedup 1.0000x reference)
//
#include <hip/hip_runtime.h>

// TT layer collapses to a block-diagonal 8x8 transform:
//   out[b, p*8+m] = sum_j x[b, p*8+j] * M[j][m] + bias[(p%512)*8+m]
// where M = A0(8x24) @ A1(24x24) @ A2(24x24) @ A3(24x8),
//   A0 = cores[1344:1536], A1 = cores[768:1344], A2 = cores[192:768], A3 = cores[0:192]
// (all reshapes in the reference are flat reinterprets; no transposes occur).

// Kernel 1: fold the 4 TT cores into the 8x8 matrix M (one workgroup, tiny).
__global__ void tt_fold_cores(const float* __restrict__ cores, float* __restrict__ M) {
    __shared__ float c[1536];
    __shared__ float T1[8 * 24];
    __shared__ float T2[8 * 24];
    const int t = threadIdx.x;  // 256 threads
    for (int i = t; i < 1536; i += 256) c[i] = cores[i];
    __syncthreads();
    const float* A0 = c + 1344;  // (8,24)
    const float* A1 = c + 768;   // (24,24)
    const float* A2 = c + 192;   // (24,24)
    const float* A3 = c + 0;     // (24,8)
    if (t < 192) {               // T1 = A0 @ A1  (8x24)
        int r = t / 24, k = t % 24;
        float s = 0.f;
        #pragma unroll
        for (int j = 0; j < 24; ++j) s = fmaf(A0[r * 24 + j], A1[j * 24 + k], s);
        T1[t] = s;
    }
    __syncthreads();
    if (t < 192) {               // T2 = T1 @ A2  (8x24)
        int r = t / 24, k = t % 24;
        float s = 0.f;
        #pragma unroll
        for (int j = 0; j < 24; ++j) s = fmaf(T1[r * 24 + j], A2[j * 24 + k], s);
        T2[t] = s;
    }
    __syncthreads();
    if (t < 64) {                // M = T2 @ A3   (8x8)
        int r = t / 8, m = t % 8;
        float s = 0.f;
        #pragma unroll
        for (int j = 0; j < 24; ++j) s = fmaf(T2[r * 24 + j], A3[j * 8 + m], s);
        M[t] = s;
    }
}

// Kernel 2: streaming apply. One 8-element block per grid-stride iteration.
__global__ void __launch_bounds__(256) tt_apply(const float* __restrict__ x,
                                                const float* __restrict__ M,
                                                const float* __restrict__ bias,
                                                float* __restrict__ out,
                                                int nblocks) {
    __shared__ float Ms[64];
    if (threadIdx.x < 64) Ms[threadIdx.x] = M[threadIdx.x];
    __syncthreads();

    const int tid = blockIdx.x * blockDim.x + threadIdx.x;
    const int stride = gridDim.x * blockDim.x;
    for (int p = tid; p < nblocks; p += stride) {
        const float4* xp = reinterpret_cast<const float4*>(x + (size_t)p * 8);
        float4 a = xp[0];
        float4 b = xp[1];
        float xv[8] = {a.x, a.y, a.z, a.w, b.x, b.y, b.z, b.w};

        const int col = (p & 511) * 8;  // output column base within the 4096-wide row
        const float4* bp = reinterpret_cast<const float4*>(bias + col);
        float4 b0 = bp[0];
        float4 b1 = bp[1];
        float acc[8] = {b0.x, b0.y, b0.z, b0.w, b1.x, b1.y, b1.z, b1.w};

        #pragma unroll
        for (int j = 0; j < 8; ++j) {
            const float xj = xv[j];
            #pragma unroll
            for (int m = 0; m < 8; ++m) acc[m] = fmaf(xj, Ms[j * 8 + m], acc[m]);
        }

        float4 o0 = {acc[0], acc[1], acc[2], acc[3]};
        float4 o1 = {acc[4], acc[5], acc[6], acc[7]};
        float4* op = reinterpret_cast<float4*>(out + (size_t)p * 8);
        op[0] = o0;
        op[1] = o1;
    }
}

extern "C" void kernel_launch(void* const* d_in, const int* in_sizes, int n_in,
                              void* d_out, int out_size, void* d_ws, size_t ws_size,
                              hipStream_t stream) {
    const float* x     = (const float*)d_in[0];  // (8192, 4096) fp32
    const float* cores = (const float*)d_in[1];  // (1536,) fp32
    const float* bias  = (const float*)d_in[2];  // (4096,) fp32
    float* out = (float*)d_out;                  // (8192*4096,) fp32
    float* M   = (float*)d_ws;                   // 64 floats scratch

    tt_fold_cores<<<1, 256, 0, stream>>>(cores, M);

    const int nblocks = out_size / 8;  // 4,194,304
    const int threads = 256;
    const int grid = 4096;             // 1M threads, 4 blocks-of-8 each
    tt_apply<<<grid, threads, 0, stream>>>(x, M, bias, out, nblocks);
}

// Round 3
// 49.348 us; speedup vs baseline: 1.0098x; 1.0098x over previous
//
#include <hip/hip_runtime.h>

// TT layer == block-diagonal 8x8 transform:
//   out[b, p*8+m] = sum_j x[b, p*8+j] * M[j][m] + bias[(p%512)*8+m]
// M = A0(8x24)@A1(24x24)@A2(24x24)@A3(24x8), slices of cores_arr (flat reinterprets).
// Fused single kernel: every block folds the cores (10 KFLOP, negligible) then streams.
// out stores are non-temporal (nt) so x (128MB) stays resident in the 256MB L3.

typedef float f32x4 __attribute__((ext_vector_type(4)));  // native vector for nt-store

__global__ void __launch_bounds__(256) tt_fused(const float* __restrict__ x,
                                                const float* __restrict__ cores,
                                                const float* __restrict__ bias,
                                                float* __restrict__ out,
                                                int nblocks) {
    __shared__ float c[1536];
    __shared__ float T1[192];
    __shared__ float T2[192];
    __shared__ float Ms[64];
    const int t = threadIdx.x;
    for (int i = t; i < 1536; i += 256) c[i] = cores[i];
    __syncthreads();
    const float* A0 = c + 1344;  // (8,24)
    const float* A1 = c + 768;   // (24,24)
    const float* A2 = c + 192;   // (24,24)
    const float* A3 = c + 0;     // (24,8)
    if (t < 192) {               // T1 = A0 @ A1  (8x24)
        int r = t / 24, k = t % 24;
        float s = 0.f;
        #pragma unroll
        for (int j = 0; j < 24; ++j) s = fmaf(A0[r * 24 + j], A1[j * 24 + k], s);
        T1[t] = s;
    }
    __syncthreads();
    if (t < 192) {               // T2 = T1 @ A2  (8x24)
        int r = t / 24, k = t % 24;
        float s = 0.f;
        #pragma unroll
        for (int j = 0; j < 24; ++j) s = fmaf(T1[r * 24 + j], A2[j * 24 + k], s);
        T2[t] = s;
    }
    __syncthreads();
    if (t < 64) {                // M = T2 @ A3   (8x8)
        int r = t / 8, m = t % 8;
        float s = 0.f;
        #pragma unroll
        for (int j = 0; j < 24; ++j) s = fmaf(T2[r * 24 + j], A3[j * 8 + m], s);
        Ms[t] = s;
    }
    __syncthreads();

    const int tid = blockIdx.x * blockDim.x + threadIdx.x;
    const int stride = gridDim.x * blockDim.x;
    for (int p = tid; p < nblocks; p += stride) {
        const float4* xp = reinterpret_cast<const float4*>(x + (size_t)p * 8);
        float4 a = xp[0];
        float4 b = xp[1];
        float xv[8] = {a.x, a.y, a.z, a.w, b.x, b.y, b.z, b.w};

        const int col = (p & 511) * 8;  // bias offset within the 4096-wide row
        const float4* bp = reinterpret_cast<const float4*>(bias + col);
        float4 b0 = bp[0];
        float4 b1 = bp[1];
        float acc[8] = {b0.x, b0.y, b0.z, b0.w, b1.x, b1.y, b1.z, b1.w};

        #pragma unroll
        for (int j = 0; j < 8; ++j) {
            const float xj = xv[j];
            #pragma unroll
            for (int m = 0; m < 8; ++m) acc[m] = fmaf(xj, Ms[j * 8 + m], acc[m]);
        }

        f32x4 o0 = {acc[0], acc[1], acc[2], acc[3]};
        f32x4 o1 = {acc[4], acc[5], acc[6], acc[7]};
        f32x4* op = reinterpret_cast<f32x4*>(out + (size_t)p * 8);
        __builtin_nontemporal_store(o0, op);
        __builtin_nontemporal_store(o1, op + 1);
    }
}

extern "C" void kernel_launch(void* const* d_in, const int* in_sizes, int n_in,
                              void* d_out, int out_size, void* d_ws, size_t ws_size,
                              hipStream_t stream) {
    const float* x     = (const float*)d_in[0];  // (8192, 4096) fp32
    const float* cores = (const float*)d_in[1];  // (1536,) fp32
    const float* bias  = (const float*)d_in[2];  // (4096,) fp32
    float* out = (float*)d_out;                  // (8192*4096,) fp32

    const int nblocks = out_size / 8;  // 4,194,304 blocks-of-8
    const int threads = 256;
    const int grid = 2048;             // 8 blocks/CU, 8 grid-stride iters/thread
    tt_fused<<<grid, threads, 0, stream>>>(x, cores, bias, out, nblocks);
}